// Round 2
// baseline (175.202 us; speedup 1.0000x reference)
//
#include <hip/hip_runtime.h>

// RandomProjectionQuantizer: x(16,3000,80) f32, proj(320,16) f32, codebook(8192,16) f32
// out: argmin indices (16,750) int32.  STACK=4, 3000%4==0 -> no padding.

#define ROWS   12000   // 16 * 750
#define DIN    320     // 80 * 4
#define PD     16      // proj_dim
#define NCODES 8192

#define CH     512            // codes per LDS chunk
#define NCHUNK (NCODES / CH)  // 16
#define RT     3              // rows per thread
#define RPB    24             // rows per block = 8 rs-groups * RT
#define GRID   (ROWS / RPB)   // 500 blocks -> ~2 blocks/CU on 256 CUs

// ---------------- codebook normalize + pre-swizzle ----------------
// Output layout (global): word = chunk*8192 + p*512 + (cl ^ ((p>>2)<<3))
// where n = chunk*512 + cl. This makes the hot kernel's LDS staging an
// identity copy (coalesced float4 -> ds_write_b128), while LDS reads of
// cv[k] for 32 consecutive codes hit 32 distinct banks (XOR swizzle).
__global__ __launch_bounds__(256) void prep_cb(const float* __restrict__ cb,
                                               float* __restrict__ cbt) {
    int gt = blockIdx.x * 256 + threadIdx.x;      // 8192*16 threads
    int n = gt >> 4, p = gt & 15;
    float v = cb[gt];
    float ss = v * v;
    ss += __shfl_xor(ss, 1, 16);
    ss += __shfl_xor(ss, 2, 16);
    ss += __shfl_xor(ss, 4, 16);
    ss += __shfl_xor(ss, 8, 16);
    float nrm = fmaxf(sqrtf(ss), 1e-12f);
    int chunk = n >> 9;
    int cl    = n & 511;
    int kc    = p >> 2;
    cbt[chunk * (PD * CH) + p * CH + (cl ^ (kc << 3))] = v / nrm;  // div matches reference
}

// ---------------- projection + normalize ----------------
__global__ __launch_bounds__(256) void prep_xp(const float* __restrict__ x,
                                               const float* __restrict__ proj,
                                               float* __restrict__ xp) {
    int gt = blockIdx.x * 256 + threadIdx.x;      // 12000*16 threads
    int r = gt >> 4, p = gt & 15;
    const float* xr = x + (size_t)r * DIN;
    float acc = 0.f;
#pragma unroll 4
    for (int k4 = 0; k4 < DIN / 4; ++k4) {
        float4 xv = *reinterpret_cast<const float4*>(xr + k4 * 4);
        acc = fmaf(xv.x, proj[(k4 * 4 + 0) * PD + p], acc);
        acc = fmaf(xv.y, proj[(k4 * 4 + 1) * PD + p], acc);
        acc = fmaf(xv.z, proj[(k4 * 4 + 2) * PD + p], acc);
        acc = fmaf(xv.w, proj[(k4 * 4 + 3) * PD + p], acc);
    }
    float ss = acc * acc;
    ss += __shfl_xor(ss, 1, 16);
    ss += __shfl_xor(ss, 2, 16);
    ss += __shfl_xor(ss, 4, 16);
    ss += __shfl_xor(ss, 8, 16);
    xp[gt] = acc / fmaxf(sqrtf(ss), 1e-12f);
}

// ---------------- fused scores + argmin ----------------
__global__ __launch_bounds__(256, 2) void rpq_main(const float* __restrict__ xp,
                                                   const float* __restrict__ cbt,
                                                   int* __restrict__ out) {
    __shared__ __align__(16) float lds[PD * CH];   // 32 KiB, identity image of one cbt chunk

    const int tid  = threadIdx.x;
    const int cs   = tid & 31;        // code slice 0..31
    const int rs   = tid >> 5;        // row group 0..7
    const int row0 = blockIdx.x * RPB + rs * RT;

    // per-thread xp fragment: 3 rows x 16 floats, static register indexing
    float xpv[RT][PD];
#pragma unroll
    for (int r = 0; r < RT; ++r) {
        const float4* s4 = reinterpret_cast<const float4*>(xp + (size_t)(row0 + r) * PD);
#pragma unroll
        for (int q = 0; q < 4; ++q) {
            float4 v = s4[q];
            xpv[r][q * 4 + 0] = v.x;
            xpv[r][q * 4 + 1] = v.y;
            xpv[r][q * 4 + 2] = v.z;
            xpv[r][q * 4 + 3] = v.w;
        }
    }

    float bd[RT];
    int   bi[RT];
#pragma unroll
    for (int r = 0; r < RT; ++r) { bd[r] = 3.0e38f; bi[r] = 0; }

    for (int chunk = 0; chunk < NCHUNK; ++chunk) {
        // issue global loads (registers only — safe before the barrier)
        const float4* src = reinterpret_cast<const float4*>(cbt + (size_t)chunk * PD * CH);
        float4 stg[8];
#pragma unroll
        for (int it = 0; it < 8; ++it) stg[it] = src[it * 256 + tid];

        __syncthreads();               // previous chunk's compute done
        float4* l4 = reinterpret_cast<float4*>(lds);
#pragma unroll
        for (int it = 0; it < 8; ++it) l4[it * 256 + tid] = stg[it];   // ds_write_b128, identity
        __syncthreads();               // chunk staged

#pragma unroll 2
        for (int i = 0; i < CH / 32; ++i) {
            const int lcode = cs + i * 32;
            float cv[PD];
#pragma unroll
            for (int kc = 0; kc < 4; ++kc) {
                const int base = lcode ^ (kc << 3);   // 32 lanes -> 32 distinct banks
#pragma unroll
                for (int j = 0; j < 4; ++j)
                    cv[kc * 4 + j] = lds[(kc * 4 + j) * CH + base];
            }
            const int gcode = chunk * CH + lcode;
#pragma unroll
            for (int r = 0; r < RT; ++r) {
                float s = 0.f;
#pragma unroll
                for (int k = 0; k < PD; ++k) s = fmaf(xpv[r][k], cv[k], s);
                float dd = 2.0f - 2.0f * s;           // contracts to fma == reference rounding
                if (dd < bd[r]) { bd[r] = dd; bi[r] = gcode; }  // strict <, ascending codes
            }
        }
    }

    // reduce across the 32 code-slices of each row group (lanes share half-wave)
#pragma unroll
    for (int r = 0; r < RT; ++r) {
        unsigned ub = __float_as_uint(bd[r]);
        ub = (ub & 0x80000000u) ? ~ub : (ub | 0x80000000u);   // monotone total order
        unsigned long long key = ((unsigned long long)ub << 32) | (unsigned)bi[r];
#pragma unroll
        for (int off = 16; off >= 1; off >>= 1) {
            unsigned long long o = __shfl_xor(key, off, 32);
            key = (o < key) ? o : key;   // min dist, tie -> min index
        }
        if (cs == 0) out[row0 + r] = (int)(key & 0xFFFFFFFFu);
    }
}

extern "C" void kernel_launch(void* const* d_in, const int* in_sizes, int n_in,
                              void* d_out, int out_size, void* d_ws, size_t ws_size,
                              hipStream_t stream) {
    const float* x    = (const float*)d_in[0];   // 16*3000*80
    const float* proj = (const float*)d_in[1];   // 320*16
    const float* cb   = (const float*)d_in[2];   // 8192*16
    int* out = (int*)d_out;                      // 12000 int32

    float* cbt = (float*)d_ws;                                              // 512 KiB
    float* xp  = (float*)((char*)d_ws + (size_t)NCODES * PD * sizeof(float)); // 768 KiB

    prep_cb<<<(NCODES * PD) / 256, 256, 0, stream>>>(cb, cbt);
    prep_xp<<<(ROWS * PD) / 256, 256, 0, stream>>>(x, proj, xp);
    rpq_main<<<GRID, 256, 0, stream>>>(xp, cbt, out);
}